// Round 6
// baseline (509.810 us; speedup 1.0000x reference)
//
#include <hip/hip_runtime.h>
#include <stdint.h>

// Problem constants (fixed by setup_inputs; all tensors f32)
#define B_ROWS 4096
#define D_IN   784
#define H_DIM  800
#define D_OUT  10
#define T_SIM  32
#define N_ELEM (B_ROWS * D_IN)   // 3211264 = 12544 * 256
#define CAP    384               // per-t list capacity (worst real ~270)

// ---------------------------------------------------------------------------
// Bit-exact JAX threefry2x32 (key = PRNGKey(42) = {0, 42})
// ---------------------------------------------------------------------------
__device__ __forceinline__ void threefry2x32(uint32_t k0, uint32_t k1,
                                             uint32_t& x0, uint32_t& x1) {
  uint32_t ks0 = k0, ks1 = k1, ks2 = k0 ^ k1 ^ 0x1BD11BDAu;
  x0 += ks0; x1 += ks1;
#define TF_RND(r) { x0 += x1; x1 = (x1 << (r)) | (x1 >> (32 - (r))); x1 ^= x0; }
  TF_RND(13) TF_RND(15) TF_RND(26) TF_RND(6)
  x0 += ks1; x1 += ks2 + 1u;
  TF_RND(17) TF_RND(29) TF_RND(16) TF_RND(24)
  x0 += ks2; x1 += ks0 + 2u;
  TF_RND(13) TF_RND(15) TF_RND(26) TF_RND(6)
  x0 += ks0; x1 += ks1 + 3u;
  TF_RND(17) TF_RND(29) TF_RND(16) TF_RND(24)
  x0 += ks1; x1 += ks2 + 4u;
  TF_RND(13) TF_RND(15) TF_RND(26) TF_RND(6)
  x0 += ks2; x1 += ks0 + 5u;
#undef TF_RND
}

// K0: x_fixed[i] = (u[i] < x[i]) ? 1 : 0, u = jax.random.uniform(key(42)),
// jax_threefry_partitionable=True: counter (0, i); bits = out0 ^ out1.
__global__ __launch_bounds__(256) void gen_xfixed(const float* __restrict__ x,
                                                  float* __restrict__ xf) {
  int i = blockIdx.x * blockDim.x + threadIdx.x;
  if (i >= N_ELEM) return;
  uint32_t c0 = 0u, c1 = (uint32_t)i;
  threefry2x32(0u, 42u, c0, c1);
  uint32_t bits = c0 ^ c1;
  float u = __uint_as_float((bits >> 9) | 0x3F800000u) - 1.0f;
  xf[i] = (u < x[i]) ? 1.0f : 0.0f;
}

// ---------------------------------------------------------------------------
// K1: cur1 = x_fixed @ W1^T + b1 in f32 — bit-exact single-accumulator
// ascending-k fma chain per element (unchanged math from the passing R5
// kernel). Optimized: +4 row padding -> 16B-aligned LDS rows so fragment
// reads are ds_read_b128 (2 LDS issues per kk instead of 8), float4 staging.
// ---------------------------------------------------------------------------
#define BM 64
#define BN 64
#define BK 16

__global__ __launch_bounds__(256) void gemm_cur1(const float* __restrict__ xf,
                                                 const float* __restrict__ W1,
                                                 const float* __restrict__ b1,
                                                 float* __restrict__ cur1) {
  __shared__ __align__(16) float As[BK][BM + 4];   // row stride 272B (16B mult)
  __shared__ __align__(16) float Bs[BK][BN + 4];
  const int m0 = blockIdx.y * BM;
  const int n0 = blockIdx.x * BN;
  const int t  = threadIdx.x;        // 0..255
  const int tx = t & 15, ty = t >> 4;
  const int sM = t >> 2;             // 0..63 staging row
  const int sK = (t & 3) * 4;        // 0,4,8,12 staging k-offset
  const int hB = n0 + sM;            // B staging source row (may be >= 800)
  float acc[4][4] = {};
  for (int kt = 0; kt < D_IN; kt += BK) {   // 784 = 49*16, ascending k
    float4 a4 = *(const float4*)&xf[(m0 + sM) * D_IN + kt + sK];
    const float4* bsrc = (hB < H_DIM)
        ? (const float4*)&W1[hB * D_IN + kt + sK]
        : (const float4*)&W1[kt + sK];            // safe dummy, zeroed below
    float4 b4 = *bsrc;
    if (hB >= H_DIM) { b4.x = 0.f; b4.y = 0.f; b4.z = 0.f; b4.w = 0.f; }
    As[sK + 0][sM] = a4.x; As[sK + 1][sM] = a4.y;
    As[sK + 2][sM] = a4.z; As[sK + 3][sM] = a4.w;
    Bs[sK + 0][sM] = b4.x; Bs[sK + 1][sM] = b4.y;
    Bs[sK + 2][sM] = b4.z; Bs[sK + 3][sM] = b4.w;
    __syncthreads();
#pragma unroll
    for (int kk = 0; kk < BK; kk++) {       // strict ascending k, single acc
      float4 av = *(const float4*)&As[kk][ty * 4];  // ds_read_b128
      float4 bv = *(const float4*)&Bs[kk][tx * 4];  // ds_read_b128
      float a[4] = {av.x, av.y, av.z, av.w};
      float b[4] = {bv.x, bv.y, bv.z, bv.w};
#pragma unroll
      for (int mi = 0; mi < 4; mi++)
#pragma unroll
        for (int ni = 0; ni < 4; ni++)
          acc[mi][ni] = __builtin_fmaf(a[mi], b[ni], acc[mi][ni]);
    }
    __syncthreads();
  }
#pragma unroll
  for (int mi = 0; mi < 4; mi++) {
    int m = m0 + ty * 4 + mi;
#pragma unroll
    for (int ni = 0; ni < 4; ni++) {
      int h = n0 + tx * 4 + ni;
      if (h < H_DIM)
        cur1[m * H_DIM + h] = acc[mi][ni] + b1[h];   // f32 add, like ref
    }
  }
}

// ---------------------------------------------------------------------------
// K2: SNN scan with per-t compacted index lists.
// Exactness argument: s += 0.0f is an exact identity (s is never -0 here),
// so the reference's ascending-h gated chain == fold over INCLUDED h only,
// ascending. Included h for time t = {h : period(h) divides t}. Lists are
// built order-preserving via wave ballot compaction. Overflow (>CAP) falls
// back to the gated full scan (same ascending order, still bit-exact).
// ---------------------------------------------------------------------------
__global__ __launch_bounds__(320) void snn_scan(const float* __restrict__ cur1,
                                                const float* __restrict__ W2,
                                                const float* __restrict__ b2,
                                                float* __restrict__ out) {
  __shared__ __align__(16) float W2P[H_DIM * D_OUT];  // [h][o], 32000 B
  __shared__ uint16_t lists[T_SIM][CAP];              // 24576 B
  __shared__ int      lenL[T_SIM];
  __shared__ uint32_t divm[T_SIM];                    // bit (p-1) <=> p | (tt+1)
  __shared__ uint8_t  periods[832];                   // padded to 13*64
  __shared__ __align__(16) float c2s[T_SIM][D_OUT];
  __shared__ float    b2f[D_OUT];

  const int tid = threadIdx.x;               // 0..319
  const int row = blockIdx.x;

  // ---- Phase A: periods (f32 chain identical to reference), staging ----
  for (int h = tid; h < H_DIM; h += 320) {
    float c = cur1[(size_t)row * H_DIM + h];
    float v = 0.0f;
    int p = 0;
#pragma unroll 1
    for (int m = 1; m <= T_SIM; m++) {
      float h1 = v + c;                      // f32 add, as reference
      if (h1 >= 1.0f) { p = m; break; }
      v = h1;
    }
    periods[h] = (uint8_t)p;
  }
  if (tid < 32) periods[H_DIM + tid] = 0;    // pad tail
  for (int e = tid; e < H_DIM * D_OUT; e += 320) {
    int h = e / D_OUT, o = e % D_OUT;
    W2P[h * D_OUT + o] = W2[o * H_DIM + h];
  }
  if (tid < D_OUT) b2f[tid] = b2[tid];
  if (tid < T_SIM) {
    uint32_t dm = 0;
    for (int p = 1; p <= T_SIM; p++)
      if ((tid + 1) % p == 0) dm |= (1u << (p - 1));
    divm[tid] = dm;
  }
  __syncthreads();

  // ---- Build: per-t ascending index lists via ballot compaction ----
  {
    const int wv = tid >> 6, ln = tid & 63;
    const uint64_t lmask = (1ull << ln) - 1ull;
    for (int tt = wv; tt < T_SIM; tt += 5) {
      const uint32_t dm = divm[tt];
      int off = 0;
      for (int ch = 0; ch < 13; ch++) {      // 13*64 = 832 (padded)
        int h = ch * 64 + ln;
        int p = periods[h];
        bool g = (p != 0) && ((dm >> ((p - 1) & 31)) & 1u);
        uint64_t b = __ballot(g);
        int pos = __popcll(b & lmask);
        if (g && (off + pos) < CAP) lists[tt][off + pos] = (uint16_t)h;
        off += __popcll(b);
      }
      if (ln == 0) lenL[tt] = off;
    }
  }
  __syncthreads();

  // ---- Exec: pure ascending adds over the included set ----
  if (tid < 160) {
    const int tt = tid & 31;                 // time index (t = tt+1)
    const int j  = tid >> 5;                 // o-pair 0..4
    float a0 = 0.0f, a1 = 0.0f;
    const int L = lenL[tt];
    if (L <= CAP) {
#pragma unroll 4
      for (int i = 0; i < L; i++) {
        int e = lists[tt][i];
        float2 w = *(const float2*)&W2P[e * D_OUT + 2 * j];
        a0 += w.x;                           // exact: included-only chain
        a1 += w.y;
      }
    } else {                                 // overflow fallback: gated scan
      const uint32_t dm = divm[tt];
#pragma unroll 4
      for (int h = 0; h < H_DIM; h++) {
        int p = periods[h];
        bool g = (p != 0) && ((dm >> ((p - 1) & 31)) & 1u);
        float2 w = *(const float2*)&W2P[h * D_OUT + 2 * j];
        a0 += g ? w.x : 0.0f;
        a1 += g ? w.y : 0.0f;
      }
    }
    c2s[tt][2 * j]     = a0;
    c2s[tt][2 * j + 1] = a1;
  }
  __syncthreads();

  // ---- Phase D: layer-2 IF scan + spike count (exact f32 ref order) ----
  if (tid < D_OUT) {
    const int o = tid;
    const float bb = b2f[o];
    float v = 0.0f; int cnt = 0;
#pragma unroll
    for (int tt = 0; tt < T_SIM; tt++) {
      float cur2 = c2s[tt][o] + bb;          // f32 add of b2, like ref
      float h2 = v + cur2;                   // f32 add
      bool spk = (h2 >= 1.0f);
      cnt += spk ? 1 : 0;
      v = spk ? 0.0f : h2;
    }
    out[(size_t)row * D_OUT + o] = (float)cnt;
  }
}

// ---------------------------------------------------------------------------
extern "C" void kernel_launch(void* const* d_in, const int* in_sizes, int n_in,
                              void* d_out, int out_size, void* d_ws, size_t ws_size,
                              hipStream_t stream) {
  const float* x  = (const float*)d_in[0];
  const float* W1 = (const float*)d_in[1];
  const float* b1 = (const float*)d_in[2];
  const float* W2 = (const float*)d_in[3];
  const float* b2 = (const float*)d_in[4];
  float* outp = (float*)d_out;

  float* xf   = (float*)d_ws;                      // N_ELEM f32 (12.85 MB)
  float* cur1 = xf + N_ELEM;                       // B*H  f32 (13.1 MB)

  gen_xfixed<<<N_ELEM / 256, 256, 0, stream>>>(x, xf);

  dim3 g1((H_DIM + BN - 1) / BN, B_ROWS / BM);     // 13 x 64
  gemm_cur1<<<g1, 256, 0, stream>>>(xf, W1, b1, cur1);

  snn_scan<<<B_ROWS, 320, 0, stream>>>(cur1, W2, b2, outp);
}

// Round 7
// 474.519 us; speedup vs baseline: 1.0744x; 1.0744x over previous
//
#include <hip/hip_runtime.h>
#include <stdint.h>

// Problem constants (fixed by setup_inputs; all tensors f32)
#define B_ROWS 4096
#define D_IN   784
#define H_DIM  800
#define D_OUT  10
#define T_SIM  32
#define N_ELEM (B_ROWS * D_IN)   // 3211264 = 12544 * 256

// ---------------------------------------------------------------------------
// Bit-exact JAX threefry2x32 (key = PRNGKey(42) = {0, 42})
// ---------------------------------------------------------------------------
__device__ __forceinline__ void threefry2x32(uint32_t k0, uint32_t k1,
                                             uint32_t& x0, uint32_t& x1) {
  uint32_t ks0 = k0, ks1 = k1, ks2 = k0 ^ k1 ^ 0x1BD11BDAu;
  x0 += ks0; x1 += ks1;
#define TF_RND(r) { x0 += x1; x1 = (x1 << (r)) | (x1 >> (32 - (r))); x1 ^= x0; }
  TF_RND(13) TF_RND(15) TF_RND(26) TF_RND(6)
  x0 += ks1; x1 += ks2 + 1u;
  TF_RND(17) TF_RND(29) TF_RND(16) TF_RND(24)
  x0 += ks2; x1 += ks0 + 2u;
  TF_RND(13) TF_RND(15) TF_RND(26) TF_RND(6)
  x0 += ks0; x1 += ks1 + 3u;
  TF_RND(17) TF_RND(29) TF_RND(16) TF_RND(24)
  x0 += ks1; x1 += ks2 + 4u;
  TF_RND(13) TF_RND(15) TF_RND(26) TF_RND(6)
  x0 += ks2; x1 += ks0 + 5u;
#undef TF_RND
}

// K0: x_fixed[i] = (u[i] < x[i]) ? 1 : 0, u = jax.random.uniform(key(42)),
// jax_threefry_partitionable=True: counter (0, i); bits = out0 ^ out1.
__global__ __launch_bounds__(256) void gen_xfixed(const float* __restrict__ x,
                                                  float* __restrict__ xf) {
  int i = blockIdx.x * blockDim.x + threadIdx.x;
  if (i >= N_ELEM) return;
  uint32_t c0 = 0u, c1 = (uint32_t)i;
  threefry2x32(0u, 42u, c0, c1);
  uint32_t bits = c0 ^ c1;
  float u = __uint_as_float((bits >> 9) | 0x3F800000u) - 1.0f;
  xf[i] = (u < x[i]) ? 1.0f : 0.0f;
}

// ---------------------------------------------------------------------------
// K1: cur1 = x_fixed @ W1^T + b1 in f32 (M=4096, N=800, K=784).
// Bit-exact: per output element one f32 accumulator over strictly ascending
// k (BLAS chain). Tile 128x64, 8x4 acc/lane: per kk 3 ds_read_b128 feed 32
// fma (64% fma issue share vs 40% in the 4x4 version).
// ---------------------------------------------------------------------------
#define BM 128
#define BN 64
#define BK 16

__global__ __launch_bounds__(256) void gemm_cur1(const float* __restrict__ xf,
                                                 const float* __restrict__ W1,
                                                 const float* __restrict__ b1,
                                                 float* __restrict__ cur1) {
  __shared__ __align__(16) float As[BK][BM + 4];   // stride 132*4=528B (16B mult)
  __shared__ __align__(16) float Bs[BK][BN + 4];   // stride 68*4=272B (16B mult)
  const int m0 = blockIdx.y * BM;
  const int n0 = blockIdx.x * BN;
  const int t  = threadIdx.x;        // 0..255
  const int tx = t & 15, ty = t >> 4;
  const int ar = t >> 1;             // 0..127 A staging row
  const int ak = (t & 1) * 8;        // 0 or 8
  const int br = t >> 2;             // 0..63  B staging row
  const int bk = (t & 3) * 4;        // 0,4,8,12
  const int hB = n0 + br;
  const float* aptr = xf + (m0 + ar) * D_IN + ak;
  const float* bptr = W1 + ((hB < H_DIM) ? hB : 0) * D_IN + bk;
  float acc[8][4] = {};
  for (int kt = 0; kt < D_IN; kt += BK) {   // 784 = 49*16, ascending k
    float4 a0 = *(const float4*)(aptr + kt);
    float4 a1 = *(const float4*)(aptr + kt + 4);
    float4 b0 = *(const float4*)(bptr + kt);
    if (hB >= H_DIM) { b0.x = b0.y = b0.z = b0.w = 0.0f; }
    __syncthreads();                        // prev-iter LDS reads done
    As[ak + 0][ar] = a0.x; As[ak + 1][ar] = a0.y;
    As[ak + 2][ar] = a0.z; As[ak + 3][ar] = a0.w;
    As[ak + 4][ar] = a1.x; As[ak + 5][ar] = a1.y;
    As[ak + 6][ar] = a1.z; As[ak + 7][ar] = a1.w;
    Bs[bk + 0][br] = b0.x; Bs[bk + 1][br] = b0.y;
    Bs[bk + 2][br] = b0.z; Bs[bk + 3][br] = b0.w;
    __syncthreads();
#pragma unroll
    for (int kk = 0; kk < BK; kk++) {       // strict ascending k, single acc
      float4 av0 = *(const float4*)&As[kk][ty * 8];
      float4 av1 = *(const float4*)&As[kk][ty * 8 + 4];
      float4 bv  = *(const float4*)&Bs[kk][tx * 4];
      float a[8] = {av0.x, av0.y, av0.z, av0.w, av1.x, av1.y, av1.z, av1.w};
      float b[4] = {bv.x, bv.y, bv.z, bv.w};
#pragma unroll
      for (int mi = 0; mi < 8; mi++)
#pragma unroll
        for (int ni = 0; ni < 4; ni++)
          acc[mi][ni] = __builtin_fmaf(a[mi], b[ni], acc[mi][ni]);
    }
  }
  const int hOut = n0 + tx * 4;              // multiple of 4; 800%4==0
  if (hOut < H_DIM) {
    float4 bb = *(const float4*)&b1[hOut];
#pragma unroll
    for (int mi = 0; mi < 8; mi++) {
      int m = m0 + ty * 8 + mi;
      float4 r;
      r.x = acc[mi][0] + bb.x;               // f32 add, like ref
      r.y = acc[mi][1] + bb.y;
      r.z = acc[mi][2] + bb.z;
      r.w = acc[mi][3] + bb.w;
      *(float4*)&cur1[m * H_DIM + hOut] = r;
    }
  }
}

// ---------------------------------------------------------------------------
// K2: SNN scan with ONE value-packed spiking-neuron list per row.
// Exactness: reference layer-2 chain = ascending-h gated single-acc fold;
// skipping h that never spike is the identity (fmaf(0,w,s)=s); for packed
// entries, fmaf(bit, w, s) reproduces the identical rounding sequence.
// packed[i] = { mask_bits, w[0..9], pad } stride 12 floats, ascending h.
// Exec: lane=(t,o); wave sees only 11 distinct LDS addresses per entry,
// all broadcast -> zero bank conflicts, no indirection.
// ---------------------------------------------------------------------------
__global__ __launch_bounds__(320) void snn_scan(const float* __restrict__ cur1,
                                                const float* __restrict__ W2,
                                                const float* __restrict__ b2,
                                                float* __restrict__ out) {
  __shared__ __align__(16) float packed[H_DIM * 12];   // 38400 B
  __shared__ int   lenS;
  __shared__ float c2s[T_SIM][D_OUT];
  __shared__ float b2f[D_OUT];
  const int tid = threadIdx.x;               // 0..319
  const int row = blockIdx.x;

  if (tid < D_OUT) b2f[tid] = b2[tid];

  // ---- Build (wave 0): period -> mask, ballot-compact ascending h ----
  if (tid < 64) {
    const int ln = tid;
    const uint64_t lmask = (1ull << ln) - 1ull;
    int off = 0;
    for (int ch = 0; ch < 13; ch++) {        // 13*64 = 832 >= 800
      int h = ch * 64 + ln;
      uint32_t mk = 0;
      if (h < H_DIM) {
        float c = cur1[(size_t)row * H_DIM + h];
        float v = 0.0f;
        int p = 0;
#pragma unroll 1
        for (int m = 1; m <= T_SIM; m++) {
          float h1 = v + c;                  // f32 add, as reference
          if (h1 >= 1.0f) { p = m; break; }
          v = h1;
        }
        if (p) for (int s = p; s <= T_SIM; s += p) mk |= 1u << (s - 1);
      }
      bool g = (mk != 0u);
      uint64_t bal = __ballot(g);
      int pos = off + __popcll(bal & lmask);
      if (g) {
        float* dst = &packed[pos * 12];
        dst[0] = __uint_as_float(mk);
#pragma unroll
        for (int o = 0; o < D_OUT; o++)
          dst[1 + o] = W2[o * H_DIM + h];    // coalesced across lanes
      }
      off += __popcll(bal);
    }
    if (ln == 0) lenS = off;
  }
  __syncthreads();

  // ---- Exec: lane (tt = tid&31, o = tid>>5), pure broadcast stream ----
  {
    const int tt = tid & 31;
    const int o  = tid >> 5;                 // 0..9
    const int L  = lenS;
    float s = 0.0f;
#pragma unroll 4
    for (int i = 0; i < L; i++) {
      uint32_t mk = __float_as_uint(packed[i * 12]);
      float w = packed[i * 12 + 1 + o];
      float g = (float)((mk >> tt) & 1u);
      s = __builtin_fmaf(g, w, s);           // exact gated chain step
    }
    c2s[tt][o] = s;
  }
  __syncthreads();

  // ---- Layer-2 IF scan + spike count (exact f32 ref order) ----
  if (tid < D_OUT) {
    const int o = tid;
    const float bb = b2f[o];
    float v = 0.0f; int cnt = 0;
#pragma unroll
    for (int tt = 0; tt < T_SIM; tt++) {
      float cur2 = c2s[tt][o] + bb;          // f32 add of b2, like ref
      float h2 = v + cur2;                   // f32 add
      bool spk = (h2 >= 1.0f);
      cnt += spk ? 1 : 0;
      v = spk ? 0.0f : h2;
    }
    out[(size_t)row * D_OUT + o] = (float)cnt;
  }
}

// ---------------------------------------------------------------------------
extern "C" void kernel_launch(void* const* d_in, const int* in_sizes, int n_in,
                              void* d_out, int out_size, void* d_ws, size_t ws_size,
                              hipStream_t stream) {
  const float* x  = (const float*)d_in[0];
  const float* W1 = (const float*)d_in[1];
  const float* b1 = (const float*)d_in[2];
  const float* W2 = (const float*)d_in[3];
  const float* b2 = (const float*)d_in[4];
  float* outp = (float*)d_out;

  float* xf   = (float*)d_ws;                      // N_ELEM f32 (12.85 MB)
  float* cur1 = xf + N_ELEM;                       // B*H  f32 (13.1 MB)

  gen_xfixed<<<N_ELEM / 256, 256, 0, stream>>>(x, xf);

  dim3 g1((H_DIM + BN - 1) / BN, B_ROWS / BM);     // 13 x 32
  gemm_cur1<<<g1, 256, 0, stream>>>(xf, W1, b1, cur1);

  snn_scan<<<B_ROWS, 320, 0, stream>>>(cur1, W2, b2, outp);
}

// Round 8
// 331.128 us; speedup vs baseline: 1.5396x; 1.4330x over previous
//
#include <hip/hip_runtime.h>
#include <stdint.h>

// Problem constants (fixed by setup_inputs; all tensors f32)
#define B_ROWS 4096
#define D_IN   784
#define H_DIM  800
#define D_OUT  10
#define T_SIM  32
#define N_ELEM (B_ROWS * D_IN)   // 3211264 = 12544 * 256
#define CAP    512               // spiking-list capacity/row (mean ~376, sd ~14)
#define R_PER  2                 // rows per snn_scan block

// ---------------------------------------------------------------------------
// Bit-exact JAX threefry2x32 (key = PRNGKey(42) = {0, 42})
// ---------------------------------------------------------------------------
__device__ __forceinline__ void threefry2x32(uint32_t k0, uint32_t k1,
                                             uint32_t& x0, uint32_t& x1) {
  uint32_t ks0 = k0, ks1 = k1, ks2 = k0 ^ k1 ^ 0x1BD11BDAu;
  x0 += ks0; x1 += ks1;
#define TF_RND(r) { x0 += x1; x1 = (x1 << (r)) | (x1 >> (32 - (r))); x1 ^= x0; }
  TF_RND(13) TF_RND(15) TF_RND(26) TF_RND(6)
  x0 += ks1; x1 += ks2 + 1u;
  TF_RND(17) TF_RND(29) TF_RND(16) TF_RND(24)
  x0 += ks2; x1 += ks0 + 2u;
  TF_RND(13) TF_RND(15) TF_RND(26) TF_RND(6)
  x0 += ks0; x1 += ks1 + 3u;
  TF_RND(17) TF_RND(29) TF_RND(16) TF_RND(24)
  x0 += ks1; x1 += ks2 + 4u;
  TF_RND(13) TF_RND(15) TF_RND(26) TF_RND(6)
  x0 += ks2; x1 += ks0 + 5u;
#undef TF_RND
}

// K0: x_fixed[i] = (u[i] < x[i]) ? 1 : 0, u = jax.random.uniform(key(42)),
// jax_threefry_partitionable=True: counter (0, i); bits = out0 ^ out1.
__global__ __launch_bounds__(256) void gen_xfixed(const float* __restrict__ x,
                                                  float* __restrict__ xf) {
  int i = blockIdx.x * blockDim.x + threadIdx.x;
  if (i >= N_ELEM) return;
  uint32_t c0 = 0u, c1 = (uint32_t)i;
  threefry2x32(0u, 42u, c0, c1);
  uint32_t bits = c0 ^ c1;
  float u = __uint_as_float((bits >> 9) | 0x3F800000u) - 1.0f;
  xf[i] = (u < x[i]) ? 1.0f : 0.0f;
}

// ---------------------------------------------------------------------------
// K1: cur1 = x_fixed @ W1^T + b1 in f32 (M=4096, N=800, K=784).
// Bit-exact: one f32 accumulator per element, strictly ascending k.
// 128x64 tile, 8x4 acc/lane. Register prefetch of tile kt+16 issued before
// the compute phase hides the global-load latency that serialized each round.
// ---------------------------------------------------------------------------
#define BM 128
#define BN 64
#define BK 16

__global__ __launch_bounds__(256) void gemm_cur1(const float* __restrict__ xf,
                                                 const float* __restrict__ W1,
                                                 const float* __restrict__ b1,
                                                 float* __restrict__ cur1) {
  __shared__ __align__(16) float As[BK][BM + 4];   // stride 528B (16B mult)
  __shared__ __align__(16) float Bs[BK][BN + 4];   // stride 272B (16B mult)
  const int m0 = blockIdx.y * BM;
  const int n0 = blockIdx.x * BN;
  const int t  = threadIdx.x;        // 0..255
  const int tx = t & 15, ty = t >> 4;
  const int ar = t >> 1;             // 0..127 A staging row
  const int ak = (t & 1) * 8;        // 0 or 8
  const int br = t >> 2;             // 0..63  B staging row
  const int bk = (t & 3) * 4;        // 0,4,8,12
  const int hB = n0 + br;
  const bool bOK = (hB < H_DIM);
  const float* aptr = xf + (m0 + ar) * D_IN + ak;
  const float* bptr = W1 + (bOK ? hB : 0) * D_IN + bk;

  float4 a0 = *(const float4*)(aptr);
  float4 a1 = *(const float4*)(aptr + 4);
  float4 b0 = *(const float4*)(bptr);
  if (!bOK) { b0.x = b0.y = b0.z = b0.w = 0.0f; }

  float acc[8][4] = {};
  for (int kt = 0; kt < D_IN; kt += BK) {   // 784 = 49*16, ascending k
    As[ak + 0][ar] = a0.x; As[ak + 1][ar] = a0.y;
    As[ak + 2][ar] = a0.z; As[ak + 3][ar] = a0.w;
    As[ak + 4][ar] = a1.x; As[ak + 5][ar] = a1.y;
    As[ak + 6][ar] = a1.z; As[ak + 7][ar] = a1.w;
    Bs[bk + 0][br] = b0.x; Bs[bk + 1][br] = b0.y;
    Bs[bk + 2][br] = b0.z; Bs[bk + 3][br] = b0.w;
    __syncthreads();
    if (kt + BK < D_IN) {                   // prefetch next tile (in flight
      a0 = *(const float4*)(aptr + kt + BK);        //  during compute)
      a1 = *(const float4*)(aptr + kt + BK + 4);
      b0 = *(const float4*)(bptr + kt + BK);
      if (!bOK) { b0.x = b0.y = b0.z = b0.w = 0.0f; }
    }
#pragma unroll
    for (int kk = 0; kk < BK; kk++) {       // strict ascending k, single acc
      float4 av0 = *(const float4*)&As[kk][ty * 8];
      float4 av1 = *(const float4*)&As[kk][ty * 8 + 4];
      float4 bv  = *(const float4*)&Bs[kk][tx * 4];
      float a[8] = {av0.x, av0.y, av0.z, av0.w, av1.x, av1.y, av1.z, av1.w};
      float b[4] = {bv.x, bv.y, bv.z, bv.w};
#pragma unroll
      for (int mi = 0; mi < 8; mi++)
#pragma unroll
        for (int ni = 0; ni < 4; ni++)
          acc[mi][ni] = __builtin_fmaf(a[mi], b[ni], acc[mi][ni]);
    }
    __syncthreads();                        // LDS reads done before overwrite
  }
  const int hOut = n0 + tx * 4;
  if (hOut < H_DIM) {
    float4 bb = *(const float4*)&b1[hOut];
#pragma unroll
    for (int mi = 0; mi < 8; mi++) {
      int m = m0 + ty * 8 + mi;
      float4 r;
      r.x = acc[mi][0] + bb.x;               // f32 add, like ref
      r.y = acc[mi][1] + bb.y;
      r.z = acc[mi][2] + bb.z;
      r.w = acc[mi][3] + bb.w;
      *(float4*)&cur1[m * H_DIM + hOut] = r;
    }
  }
}

// ---------------------------------------------------------------------------
// K2: SNN scan, 2 rows/block, fully-parallel build + dense broadcast exec.
// Exactness: per (row,t,o) the reference layer-2 value is an ascending-h
// single-accumulator fold where never-spiking h contribute s+=0 (identity,
// skipped) and spiking h contribute s+=(bit? w:0) — reproduced verbatim.
// Compaction is order-preserving (ballot prefix, ascending chunks).
// ---------------------------------------------------------------------------
__global__ __launch_bounds__(320) void snn_scan(const float* __restrict__ cur1,
                                                const float* __restrict__ W2,
                                                const float* __restrict__ b2,
                                                float* __restrict__ out) {
  __shared__ uint8_t  per_s[R_PER][832];            // periods (0 = no spike)
  __shared__ uint16_t hidx[R_PER][CAP];
  __shared__ uint32_t mks[R_PER][CAP];              // spike masks, 0-padded
  __shared__ __align__(16) float wv[R_PER][CAP][D_OUT];  // 40 KB
  __shared__ int      lenL[R_PER];
  __shared__ uint32_t divm_s[T_SIM];
  __shared__ float    c2s[R_PER][T_SIM][D_OUT];
  __shared__ float    b2f[D_OUT];
  const int tid  = threadIdx.x;              // 0..319
  const int row0 = blockIdx.x * R_PER;

  if (tid < D_OUT) b2f[tid] = b2[tid];
  if (tid < T_SIM) {                         // divisor masks (fallback only)
    uint32_t dm = 0;
#pragma unroll
    for (int p = 1; p <= T_SIM; p++)
      if ((tid + 1) % p == 0) dm |= 1u << (p - 1);
    divm_s[tid] = dm;
  }

  // ---- Phase A: all threads compute periods (parallel global loads) ----
  for (int e = tid; e < R_PER * 832; e += 320) {
    int r = (e >= 832) ? 1 : 0;
    int h = e - r * 832;
    int p = 0;
    if (h < H_DIM) {
      float c = cur1[(size_t)(row0 + r) * H_DIM + h];
      float v = 0.0f;
#pragma unroll 1
      for (int m = 1; m <= T_SIM; m++) {
        float h1 = v + c;                    // f32 add, as reference
        if (h1 >= 1.0f) { p = m; break; }
        v = h1;
      }
    }
    per_s[r][h] = (uint8_t)p;
  }
  __syncthreads();

  // ---- Phase B: 2 waves compact indices (no memory latency in chain) ----
  if (tid < 128) {
    const int r = tid >> 6, ln = tid & 63;
    const uint64_t lmask = (1ull << ln) - 1ull;
    int off = 0;
    for (int ch = 0; ch < 13; ch++) {        // 13*64 = 832
      int h = ch * 64 + ln;
      int p = per_s[r][h];
      bool g = (p != 0);
      uint64_t bal = __ballot(g);
      int pos = off + __popcll(bal & lmask);
      if (g && pos < CAP) {
        hidx[r][pos] = (uint16_t)h;
        uint32_t mk = 0;
        for (int s = p; s <= T_SIM; s += p) mk |= 1u << (s - 1);
        mks[r][pos] = mk;
      }
      off += __popcll(bal);
    }
    if (ln == 0) lenL[r] = off;
  }
  __syncthreads();

  // ---- Phase C: all threads: zero-pad masks + gather W2 values ----
  {
    const int L0 = min(lenL[0], CAP), L1 = min(lenL[1], CAP);
    for (int e = tid; e < R_PER * CAP; e += 320) {
      int r = e >> 9, i = e & (CAP - 1);
      int Lr = r ? L1 : L0;
      if (i >= Lr) {
        mks[r][i] = 0u;                      // padding: cndmask sees bit=0
      } else {
        int h = hidx[r][i];
#pragma unroll
        for (int o = 0; o < D_OUT; o++)
          wv[r][i][o] = W2[o * H_DIM + h];   // L2-hot (W2 = 32 KB)
      }
    }
  }
  __syncthreads();

  // ---- Exec: wave j = o-pair, lanes (t, r); broadcast LDS stream ----
  {
    const int t = tid & 31, r = (tid >> 5) & 1, j = tid >> 6;  // j: 0..4
    const int Lr = lenL[r];
    float s0 = 0.0f, s1 = 0.0f;
    if (Lr <= CAP) {                         // normal path (virtually always)
      const int Lmax = max(min(lenL[0], CAP), min(lenL[1], CAP));
      const uint32_t* mp = mks[r];
      const float*    wp = &wv[r][0][2 * j];
#pragma unroll 4
      for (int i = 0; i < Lmax; i++) {
        uint32_t mk = mp[i];
        float2 w = *(const float2*)wp; wp += D_OUT;
        bool g = (mk >> t) & 1u;
        s0 += g ? w.x : 0.0f;                // identical op to ref (+w or +0)
        s1 += g ? w.y : 0.0f;
      }
    } else {                                 // overflow fallback: gated scan
      const uint32_t dm = divm_s[t];
      for (int h = 0; h < H_DIM; h++) {
        int p = per_s[r][h];
        bool g = p && ((dm >> (p - 1)) & 1u);
        float w0 = W2[(2 * j) * H_DIM + h];
        float w1 = W2[(2 * j + 1) * H_DIM + h];
        s0 += g ? w0 : 0.0f;
        s1 += g ? w1 : 0.0f;
      }
    }
    c2s[r][t][2 * j]     = s0;
    c2s[r][t][2 * j + 1] = s1;
  }
  __syncthreads();

  // ---- Layer-2 IF scan + spike count (exact f32 ref order) ----
  if (tid < R_PER * D_OUT) {
    const int r = tid / D_OUT, o = tid % D_OUT;
    const float bb = b2f[o];
    float v = 0.0f; int cnt = 0;
#pragma unroll
    for (int t = 0; t < T_SIM; t++) {
      float cur2 = c2s[r][t][o] + bb;        // f32 add of b2, like ref
      float h2 = v + cur2;                   // f32 add
      bool spk = (h2 >= 1.0f);
      cnt += spk ? 1 : 0;
      v = spk ? 0.0f : h2;
    }
    out[(size_t)(row0 + r) * D_OUT + o] = (float)cnt;
  }
}

// ---------------------------------------------------------------------------
extern "C" void kernel_launch(void* const* d_in, const int* in_sizes, int n_in,
                              void* d_out, int out_size, void* d_ws, size_t ws_size,
                              hipStream_t stream) {
  const float* x  = (const float*)d_in[0];
  const float* W1 = (const float*)d_in[1];
  const float* b1 = (const float*)d_in[2];
  const float* W2 = (const float*)d_in[3];
  const float* b2 = (const float*)d_in[4];
  float* outp = (float*)d_out;

  float* xf   = (float*)d_ws;                      // N_ELEM f32 (12.85 MB)
  float* cur1 = xf + N_ELEM;                       // B*H  f32 (13.1 MB)

  gen_xfixed<<<N_ELEM / 256, 256, 0, stream>>>(x, xf);

  dim3 g1((H_DIM + BN - 1) / BN, B_ROWS / BM);     // 13 x 32
  gemm_cur1<<<g1, 256, 0, stream>>>(xf, W1, b1, cur1);

  snn_scan<<<B_ROWS / R_PER, 320, 0, stream>>>(cur1, W2, b2, outp);
}

// Round 9
// 296.787 us; speedup vs baseline: 1.7178x; 1.1157x over previous
//
#include <hip/hip_runtime.h>
#include <stdint.h>

// Problem constants (fixed by setup_inputs; all tensors f32)
#define B_ROWS 4096
#define D_IN   784
#define H_DIM  800
#define D_OUT  10
#define T_SIM  32
#define N_ELEM (B_ROWS * D_IN)   // 3211264 = 12544 * 256
#define CAP    448               // spiking-list cap/row (mean ~376, sd ~14)
#define R_PER  2                 // rows per snn_scan block

// ---------------------------------------------------------------------------
// Bit-exact JAX threefry2x32 (key = PRNGKey(42) = {0, 42})
// ---------------------------------------------------------------------------
__device__ __forceinline__ void threefry2x32(uint32_t k0, uint32_t k1,
                                             uint32_t& x0, uint32_t& x1) {
  uint32_t ks0 = k0, ks1 = k1, ks2 = k0 ^ k1 ^ 0x1BD11BDAu;
  x0 += ks0; x1 += ks1;
#define TF_RND(r) { x0 += x1; x1 = (x1 << (r)) | (x1 >> (32 - (r))); x1 ^= x0; }
  TF_RND(13) TF_RND(15) TF_RND(26) TF_RND(6)
  x0 += ks1; x1 += ks2 + 1u;
  TF_RND(17) TF_RND(29) TF_RND(16) TF_RND(24)
  x0 += ks2; x1 += ks0 + 2u;
  TF_RND(13) TF_RND(15) TF_RND(26) TF_RND(6)
  x0 += ks0; x1 += ks1 + 3u;
  TF_RND(17) TF_RND(29) TF_RND(16) TF_RND(24)
  x0 += ks1; x1 += ks2 + 4u;
  TF_RND(13) TF_RND(15) TF_RND(26) TF_RND(6)
  x0 += ks2; x1 += ks0 + 5u;
#undef TF_RND
}

// K0: x_fixed[i] = (u[i] < x[i]) ? 1 : 0, u = jax.random.uniform(key(42)),
// jax_threefry_partitionable=True: counter (0, i); bits = out0 ^ out1.
__global__ __launch_bounds__(256) void gen_xfixed(const float* __restrict__ x,
                                                  float* __restrict__ xf) {
  int i = blockIdx.x * blockDim.x + threadIdx.x;
  if (i >= N_ELEM) return;
  uint32_t c0 = 0u, c1 = (uint32_t)i;
  threefry2x32(0u, 42u, c0, c1);
  uint32_t bits = c0 ^ c1;
  float u = __uint_as_float((bits >> 9) | 0x3F800000u) - 1.0f;
  xf[i] = (u < x[i]) ? 1.0f : 0.0f;
}

// ---------------------------------------------------------------------------
// K1: fused  cur1 = x_fixed @ W1^T + b1 (bit-exact f32 ascending-k single-
// accumulator chain)  +  layer-1 IF period computed in the epilogue from the
// register-resident cur1 value (identical f32 add chain to the reference
// scan). Output: per-neuron period byte pb[row][h] (0 = never spikes).
// cur1 never touches memory.
// ---------------------------------------------------------------------------
#define BM 128
#define BN 64
#define BK 16

__global__ __launch_bounds__(256) void gemm_periods(const float* __restrict__ xf,
                                                    const float* __restrict__ W1,
                                                    const float* __restrict__ b1,
                                                    uint8_t* __restrict__ pb) {
  __shared__ __align__(16) float As[BK][BM + 4];   // stride 528B (16B mult)
  __shared__ __align__(16) float Bs[BK][BN + 4];   // stride 272B (16B mult)
  const int m0 = blockIdx.y * BM;
  const int n0 = blockIdx.x * BN;
  const int t  = threadIdx.x;        // 0..255
  const int tx = t & 15, ty = t >> 4;
  const int ar = t >> 1;             // 0..127 A staging row
  const int ak = (t & 1) * 8;        // 0 or 8
  const int br = t >> 2;             // 0..63  B staging row
  const int bk = (t & 3) * 4;        // 0,4,8,12
  const int hB = n0 + br;
  const bool bOK = (hB < H_DIM);
  const float* aptr = xf + (m0 + ar) * D_IN + ak;
  const float* bptr = W1 + (bOK ? hB : 0) * D_IN + bk;

  float4 a0 = *(const float4*)(aptr);
  float4 a1 = *(const float4*)(aptr + 4);
  float4 b0 = *(const float4*)(bptr);
  if (!bOK) { b0.x = b0.y = b0.z = b0.w = 0.0f; }

  float acc[8][4] = {};
  for (int kt = 0; kt < D_IN; kt += BK) {   // 784 = 49*16, ascending k
    As[ak + 0][ar] = a0.x; As[ak + 1][ar] = a0.y;
    As[ak + 2][ar] = a0.z; As[ak + 3][ar] = a0.w;
    As[ak + 4][ar] = a1.x; As[ak + 5][ar] = a1.y;
    As[ak + 6][ar] = a1.z; As[ak + 7][ar] = a1.w;
    Bs[bk + 0][br] = b0.x; Bs[bk + 1][br] = b0.y;
    Bs[bk + 2][br] = b0.z; Bs[bk + 3][br] = b0.w;
    __syncthreads();
    if (kt + BK < D_IN) {                   // prefetch next tile
      a0 = *(const float4*)(aptr + kt + BK);
      a1 = *(const float4*)(aptr + kt + BK + 4);
      b0 = *(const float4*)(bptr + kt + BK);
      if (!bOK) { b0.x = b0.y = b0.z = b0.w = 0.0f; }
    }
#pragma unroll
    for (int kk = 0; kk < BK; kk++) {       // strict ascending k, single acc
      float4 av0 = *(const float4*)&As[kk][ty * 8];
      float4 av1 = *(const float4*)&As[kk][ty * 8 + 4];
      float4 bv  = *(const float4*)&Bs[kk][tx * 4];
      float a[8] = {av0.x, av0.y, av0.z, av0.w, av1.x, av1.y, av1.z, av1.w};
      float b[4] = {bv.x, bv.y, bv.z, bv.w};
#pragma unroll
      for (int mi = 0; mi < 8; mi++)
#pragma unroll
        for (int ni = 0; ni < 4; ni++)
          acc[mi][ni] = __builtin_fmaf(a[mi], b[ni], acc[mi][ni]);
    }
    __syncthreads();                        // LDS reads done before overwrite
  }
  const int hOut = n0 + tx * 4;
  if (hOut < H_DIM) {
    float4 bb = *(const float4*)&b1[hOut];
#pragma unroll
    for (int mi = 0; mi < 8; mi++) {
      int m = m0 + ty * 8 + mi;
      float c4[4];
      c4[0] = acc[mi][0] + bb.x;            // f32 add of b1, like ref
      c4[1] = acc[mi][1] + bb.y;
      c4[2] = acc[mi][2] + bb.z;
      c4[3] = acc[mi][3] + bb.w;
      uint32_t packed = 0;
#pragma unroll
      for (int ni = 0; ni < 4; ni++) {
        float c = c4[ni];
        float v = 0.0f;
        int p = 0;
#pragma unroll 1
        for (int s = 1; s <= T_SIM; s++) {
          float h1 = v + c;                 // f32 add, as reference
          if (h1 >= 1.0f) { p = s; break; } // heaviside(h1 - 1) >= 0
          v = h1;
        }
        packed |= (uint32_t)p << (8 * ni);
      }
      *(uint32_t*)&pb[(size_t)m * H_DIM + hOut] = packed;  // 4-aligned
    }
  }
}

// ---------------------------------------------------------------------------
// K2: SNN scan from period bytes. W2T staged once per block (shared by both
// rows); compact list stores haddr = h*40 (uint16) + spike mask, ascending h.
// Exec: lanes (t, r), wave = o-pair j; all LDS reads are <=2-distinct
// broadcasts. Exactness: ascending-h single-acc gated fold == reference
// (skip of never-spiking h is the +0 identity; +w / +0 ops verbatim).
// ---------------------------------------------------------------------------
__global__ __launch_bounds__(320) void snn_scan(const uint8_t* __restrict__ pb,
                                                const float* __restrict__ W2,
                                                const float* __restrict__ b2,
                                                float* __restrict__ out) {
  __shared__ __align__(16) float W2T[H_DIM * D_OUT];  // [h][o], 32000 B
  __shared__ uint16_t ha16[R_PER][CAP];               // h*40, 0-padded
  __shared__ uint32_t mks[R_PER][CAP];                // spike masks, 0-padded
  __shared__ int      lenL[R_PER];
  __shared__ uint32_t mask_tbl[T_SIM + 1];
  __shared__ float    c2s[R_PER][T_SIM][D_OUT];
  __shared__ float    b2f[D_OUT];
  const int tid  = threadIdx.x;              // 0..319
  const int row0 = blockIdx.x * R_PER;

  if (tid < D_OUT) b2f[tid] = b2[tid];
  if (tid <= T_SIM) {                        // mask of multiples of p
    uint32_t mk = 0;
    if (tid > 0) for (int s = tid; s <= T_SIM; s += tid) mk |= 1u << (s - 1);
    mask_tbl[tid] = mk;
  }
  __syncthreads();

  // ---- Build (2 waves) || W2T staging (3 waves) ----
  if (tid < 128) {
    const int r = tid >> 6, ln = tid & 63;
    const uint64_t lmask = (1ull << ln) - 1ull;
    uint8_t pv[13];
#pragma unroll
    for (int ch = 0; ch < 13; ch++) {        // coalesced, independent loads
      int h = ch * 64 + ln;
      pv[ch] = (h < H_DIM) ? pb[(size_t)(row0 + r) * H_DIM + h] : (uint8_t)0;
    }
    int off = 0;
#pragma unroll
    for (int ch = 0; ch < 13; ch++) {
      int h = ch * 64 + ln;
      int p = pv[ch];
      bool g = (p != 0);
      uint64_t bal = __ballot(g);
      int pos = off + __popcll(bal & lmask);
      if (g && pos < CAP) {
        ha16[r][pos] = (uint16_t)(h * 40);   // byte offset into W2T row
        mks[r][pos]  = mask_tbl[p];
      }
      off += __popcll(bal);
    }
    if (ln == 0) lenL[r] = off;
  } else {
    for (int e = tid - 128; e < H_DIM * D_OUT; e += 192) {
      int o = e / H_DIM, h = e - o * H_DIM;
      W2T[h * D_OUT + o] = W2[e];            // coalesced global read
    }
  }
  __syncthreads();

  // ---- Zero-pad lists to uniform length ----
  const int L0 = min(lenL[0], CAP), L1 = min(lenL[1], CAP);
  for (int e = tid; e < R_PER * CAP; e += 320) {
    int r = e / CAP, i = e - r * CAP;
    if (i >= (r ? L1 : L0)) { mks[r][i] = 0u; ha16[r][i] = 0; }
  }
  __syncthreads();

  // ---- Exec: wave j = o-pair, lanes (t, r); broadcast LDS stream ----
  {
    const int t = tid & 31, r = (tid >> 5) & 1, j = tid >> 6;  // j: 0..4
    float s0 = 0.0f, s1 = 0.0f;
    if (lenL[0] <= CAP && lenL[1] <= CAP) {  // normal path (virtually always)
      const int Lmax = max(L0, L1);
      const uint16_t* hp = ha16[r];
      const uint32_t* mp = mks[r];
      const float*    wbase = W2T + 2 * j;   // + haddr/4 floats
#pragma unroll 8
      for (int i = 0; i < Lmax; i++) {
        uint32_t ha = hp[i];                 // 2 distinct/wave: broadcast
        uint32_t mk = mp[i];                 // 2 distinct/wave: broadcast
        float2 w = *(const float2*)((const char*)wbase + ha);  // broadcast
        bool g = (mk >> t) & 1u;
        s0 += g ? w.x : 0.0f;                // identical op to ref (+w or +0)
        s1 += g ? w.y : 0.0f;
      }
    } else {                                 // overflow fallback: gated scan
      const uint8_t* prow = pb + (size_t)(row0 + r) * H_DIM;
      for (int h = 0; h < H_DIM; h++) {
        uint32_t mk = mask_tbl[prow[h]];
        float2 w = *(const float2*)&W2T[h * D_OUT + 2 * j];
        bool g = (mk >> t) & 1u;
        s0 += g ? w.x : 0.0f;
        s1 += g ? w.y : 0.0f;
      }
    }
    c2s[r][t][2 * j]     = s0;
    c2s[r][t][2 * j + 1] = s1;
  }
  __syncthreads();

  // ---- Layer-2 IF scan + spike count (exact f32 ref order) ----
  if (tid < R_PER * D_OUT) {
    const int r = tid / D_OUT, o = tid % D_OUT;
    const float bb = b2f[o];
    float v = 0.0f; int cnt = 0;
#pragma unroll
    for (int t = 0; t < T_SIM; t++) {
      float cur2 = c2s[r][t][o] + bb;        // f32 add of b2, like ref
      float h2 = v + cur2;                   // f32 add
      bool spk = (h2 >= 1.0f);
      cnt += spk ? 1 : 0;
      v = spk ? 0.0f : h2;
    }
    out[(size_t)(row0 + r) * D_OUT + o] = (float)cnt;
  }
}

// ---------------------------------------------------------------------------
extern "C" void kernel_launch(void* const* d_in, const int* in_sizes, int n_in,
                              void* d_out, int out_size, void* d_ws, size_t ws_size,
                              hipStream_t stream) {
  const float* x  = (const float*)d_in[0];
  const float* W1 = (const float*)d_in[1];
  const float* b1 = (const float*)d_in[2];
  const float* W2 = (const float*)d_in[3];
  const float* b2 = (const float*)d_in[4];
  float* outp = (float*)d_out;

  float*   xf = (float*)d_ws;                       // N_ELEM f32 (12.85 MB)
  uint8_t* pbuf = (uint8_t*)(xf + N_ELEM);          // B*H bytes  (3.28 MB)

  gen_xfixed<<<N_ELEM / 256, 256, 0, stream>>>(x, xf);

  dim3 g1((H_DIM + BN - 1) / BN, B_ROWS / BM);      // 13 x 32
  gemm_periods<<<g1, 256, 0, stream>>>(xf, W1, b1, pbuf);

  snn_scan<<<B_ROWS / R_PER, 320, 0, stream>>>(pbuf, W2, b2, outp);
}